// Round 8
// baseline (306.154 us; speedup 1.0000x reference)
//
#include <hip/hip_runtime.h>
#include <hip/hip_bf16.h>
#include <cstdint>

#define TOKENS 8192
#define DIN 1024
#define DOUT 1024
#define NE 8

typedef __bf16 bf16;
typedef __attribute__((ext_vector_type(8))) __bf16 bf16x8;
typedef __attribute__((ext_vector_type(4))) float floatx4;
typedef __attribute__((ext_vector_type(2))) float floatx2;

// async global->LDS, 16B per lane. LDS dest must be wave-uniform base + lane*16.
__device__ __forceinline__ void async16(const void* gptr, void* lptr) {
  __builtin_amdgcn_global_load_lds(
      (const __attribute__((address_space(1))) void*)gptr,
      (__attribute__((address_space(3))) void*)lptr,
      16, 0, 0);
}

// ---------------------------------------------------------------------------
// Fused prep: blocks [0,2048) = gate softmax + x->bf16; blocks [2048,4096) =
// W[e][i][o] fp32 -> Wt[e][o][i] bf16 transpose.
// ---------------------------------------------------------------------------
__global__ __launch_bounds__(256) void prep_kernel(
    const float* __restrict__ x, const float* __restrict__ gw,
    const float* __restrict__ gb, float* __restrict__ g,
    bf16* __restrict__ xb, const float* __restrict__ w,
    bf16* __restrict__ wt) {
  __shared__ float tile[64][65];

  if (blockIdx.x < 2048) {
    const int lane = threadIdx.x & 63;
    const int wave = threadIdx.x >> 6;
    const int t = blockIdx.x * 4 + wave;
    const float* xr = x + (size_t)t * DIN;
    bf16* xbr = xb + (size_t)t * DIN;

    float acc[NE];
#pragma unroll
    for (int e = 0; e < NE; ++e) acc[e] = 0.f;

#pragma unroll
    for (int it = 0; it < 8; ++it) {
      const int i = it * 128 + lane * 2;
      const floatx2 xv = *(const floatx2*)(xr + i);
      union { bf16 b[2]; uint32_t u; } cv;
      cv.b[0] = (bf16)xv[0]; cv.b[1] = (bf16)xv[1];
      *(uint32_t*)(xbr + i) = cv.u;
      const floatx4 w00 = *(const floatx4*)(gw + (size_t)i * NE);
      const floatx4 w01 = *(const floatx4*)(gw + (size_t)i * NE + 4);
      const floatx4 w10 = *(const floatx4*)(gw + (size_t)(i + 1) * NE);
      const floatx4 w11 = *(const floatx4*)(gw + (size_t)(i + 1) * NE + 4);
#pragma unroll
      for (int e = 0; e < 4; ++e) {
        acc[e]     += xv[0] * w00[e] + xv[1] * w10[e];
        acc[e + 4] += xv[0] * w01[e] + xv[1] * w11[e];
      }
    }
#pragma unroll
    for (int e = 0; e < NE; ++e) {
#pragma unroll
      for (int off = 32; off > 0; off >>= 1)
        acc[e] += __shfl_xor(acc[e], off, 64);
    }
    float lg[NE];
    float mx = -3.0e38f;
#pragma unroll
    for (int e = 0; e < NE; ++e) { lg[e] = acc[e] + gb[e]; mx = fmaxf(mx, lg[e]); }
    float s = 0.f;
#pragma unroll
    for (int e = 0; e < NE; ++e) { lg[e] = __expf(lg[e] - mx); s += lg[e]; }
    const float inv = 1.f / s;
    if (lane == 0) {
      floatx4 o0, o1;
#pragma unroll
      for (int e = 0; e < 4; ++e) { o0[e] = lg[e] * inv; o1[e] = lg[e + 4] * inv; }
      *(floatx4*)(g + (size_t)t * NE) = o0;
      *(floatx4*)(g + (size_t)t * NE + 4) = o1;
    }
  } else {
    const int b = blockIdx.x - 2048;
    const int e = b >> 8;
    const int i0 = ((b >> 4) & 15) * 64;
    const int o0 = (b & 15) * 64;
    const int tid = threadIdx.x;
    const int c4 = (tid & 15) * 4;
    const int r = tid >> 4;

    const float* src = w + ((size_t)e * DIN + i0) * DOUT + o0;
#pragma unroll
    for (int rr = r; rr < 64; rr += 16) {
      const floatx4 v = *(const floatx4*)(src + (size_t)rr * DOUT + c4);
      tile[rr][c4] = v[0]; tile[rr][c4 + 1] = v[1];
      tile[rr][c4 + 2] = v[2]; tile[rr][c4 + 3] = v[3];
    }
    __syncthreads();
    bf16* dst = wt + ((size_t)e * DOUT + o0) * DIN + i0;
#pragma unroll
    for (int rr = r; rr < 64; rr += 16) {
      union { bf16 b[4]; uint64_t u; } cv;
#pragma unroll
      for (int j = 0; j < 4; ++j) cv.b[j] = (bf16)tile[c4 + j][rr];
      *(uint64_t*)(dst + (size_t)rr * DIN + c4) = cv.u;
    }
  }
}

// ---------------------------------------------------------------------------
// Fused MoE GEMM, R8: R4's e-outer / dual-acc / BK=64 / proven swizzle, with
// PING-PONG PREFETCH: As[2],Bs[2]; each of the 128 steps issues async16 for
// the NEXT tile pair into buffer p^1, computes 32 MFMA from buffer p, then
// one __syncthreads. The barrier's vmcnt(0) drain now waits on loads that
// had the whole compute phase (~1500+ cyc >> L2 latency) in flight —
// replacing R4's 256 serialized issue->drain barriers (~1000 cyc stall/step).
// Buffer-hazard check: step s prefetches into p^1 = step s-1's read buffer;
// those ds_reads completed before barrier s-1 (syncthreads waits lgkmcnt).
// ---------------------------------------------------------------------------
__global__ __launch_bounds__(256, 2) void moe_gemm(
    const bf16* __restrict__ xb, const bf16* __restrict__ wt,
    const float* __restrict__ g, float* __restrict__ out) {
  __shared__ __align__(16) bf16 As[2][128 * 64];  // 2 x 16KB
  __shared__ __align__(16) bf16 Bs[2][128 * 64];  // 2 x 16KB

  const int tid = threadIdx.x;
  const int bm = blockIdx.x >> 3;
  const int bn = blockIdx.x & 7;
  const int lane = tid & 63;
  const int wave = tid >> 6;
  const int wm = wave >> 1, wn = wave & 1;
  const int lr = lane & 15, lq = lane >> 4;

  // staging (R4 geometry, measured conflict-free): pass j covers rows
  // 32j..32j+31; unit u=tid+256j -> row=u>>3, pos=u&7, col=(pos^(row&7))*8.
  const int srow = tid >> 3;                                  // 0..31
  const int scol = (((tid & 7) ^ (srow & 7)) << 3);           // swizzled col

  const bf16* agp = xb + ((size_t)(bm * 128 + srow)) * DIN + scol;
  const bf16* bgp = wt + ((size_t)(bn * 128 + srow)) * DIN + scol;

  const int kx = lr & 7;
  const int tok0 = bm * 128 + wm * 64;

  // initial stage: (e=0, w=0) -> buffer 0
#pragma unroll
  for (int j = 0; j < 4; ++j) {
    async16(agp + (size_t)(32 * j) * DIN, &As[0][tid * 8 + j * 2048]);
    async16(bgp + (size_t)(32 * j) * DIN, &Bs[0][tid * 8 + j * 2048]);
  }

  const floatx4 fzero = {0.f, 0.f, 0.f, 0.f};
  floatx4 accF[4][4];
#pragma unroll
  for (int im = 0; im < 4; ++im)
#pragma unroll
    for (int in = 0; in < 4; ++in) accF[im][in] = fzero;

  __syncthreads();  // drain initial stage

  int p = 0;
  for (int e = 0; e < NE; ++e) {
    floatx4 accE[4][4];
#pragma unroll
    for (int im = 0; im < 4; ++im)
#pragma unroll
      for (int in = 0; in < 4; ++in) accE[im][in] = fzero;

    for (int w = 0; w < 16; ++w) {
      // 1. prefetch next step's tiles into buffer p^1 (overlaps compute)
      const bool last = (e == NE - 1) && (w == 15);
      if (!last) {
        const int en = (w == 15) ? e + 1 : e;
        const int wnx = (w == 15) ? 0 : w + 1;
        const bf16* ap = agp + (size_t)(wnx * 64);
        const bf16* bp = bgp + ((size_t)en << 20) + (size_t)(wnx * 64);
#pragma unroll
        for (int j = 0; j < 4; ++j) {
          async16(ap + (size_t)(32 * j) * DIN, &As[p ^ 1][tid * 8 + j * 2048]);
          async16(bp + (size_t)(32 * j) * DIN, &Bs[p ^ 1][tid * 8 + j * 2048]);
        }
      }

      // 2. compute from buffer p
#pragma unroll
      for (int h = 0; h < 2; ++h) {
        const int kg = ((h * 4 + lq) ^ kx) << 3;
        bf16x8 av[4], bv[4];
#pragma unroll
        for (int im = 0; im < 4; ++im)
          av[im] = *(const bf16x8*)(&As[p][(wm * 64 + im * 16 + lr) * 64 + kg]);
#pragma unroll
        for (int in = 0; in < 4; ++in)
          bv[in] = *(const bf16x8*)(&Bs[p][(wn * 64 + in * 16 + lr) * 64 + kg]);
#pragma unroll
        for (int im = 0; im < 4; ++im)
#pragma unroll
          for (int in = 0; in < 4; ++in)
            accE[im][in] = __builtin_amdgcn_mfma_f32_16x16x32_bf16(
                av[im], bv[in], accE[im][in], 0, 0, 0);
      }

      // 3. single barrier: prefetch drained (overlapped), LDS reads retired
      __syncthreads();
      p ^= 1;
    }

    // fold: accF += g[row, e] * accE   (8 folds total — negligible)
#pragma unroll
    for (int im = 0; im < 4; ++im) {
      float gv[4];
#pragma unroll
      for (int r = 0; r < 4; ++r)
        gv[r] = g[(size_t)(tok0 + im * 16 + lq * 4 + r) * NE + e];
#pragma unroll
      for (int in = 0; in < 4; ++in)
#pragma unroll
        for (int r = 0; r < 4; ++r)
          accF[im][in][r] += gv[r] * accE[im][in][r];
    }
  }

#pragma unroll
  for (int im = 0; im < 4; ++im)
#pragma unroll
    for (int in = 0; in < 4; ++in) {
      const int col = bn * 128 + wn * 64 + in * 16 + lr;
#pragma unroll
      for (int r = 0; r < 4; ++r)
        out[(size_t)(tok0 + im * 16 + lq * 4 + r) * DOUT + col] =
            accF[im][in][r];
    }
}

// ---------------------------------------------------------------------------
extern "C" void kernel_launch(void* const* d_in, const int* in_sizes, int n_in,
                              void* d_out, int out_size, void* d_ws,
                              size_t ws_size, hipStream_t stream) {
  const float* x  = (const float*)d_in[0];
  const float* gw = (const float*)d_in[1];
  const float* gb = (const float*)d_in[2];
  const float* w  = (const float*)d_in[3];
  float* out = (float*)d_out;

  char* ws = (char*)d_ws;
  float* g  = (float*)ws;
  bf16* xb  = (bf16*)(ws + 262144);
  bf16* wt  = (bf16*)(ws + 262144 + (size_t)TOKENS * DIN * 2);

  prep_kernel<<<4096, 256, 0, stream>>>(x, gw, gb, g, xb, w, wt);
  moe_gemm<<<512, 256, 0, stream>>>(xb, wt, g, out);
}

// Round 9
// 296.130 us; speedup vs baseline: 1.0339x; 1.0339x over previous
//
#include <hip/hip_runtime.h>
#include <hip/hip_bf16.h>
#include <cstdint>

#define TOKENS 8192
#define DIN 1024
#define DOUT 1024
#define NE 8

typedef __bf16 bf16;
typedef __attribute__((ext_vector_type(8))) __bf16 bf16x8;
typedef __attribute__((ext_vector_type(4))) float floatx4;
typedef __attribute__((ext_vector_type(16))) float floatx16;
typedef __attribute__((ext_vector_type(2))) float floatx2;

// async global->LDS, 16B per lane. LDS dest must be wave-uniform base + lane*16.
__device__ __forceinline__ void async16(const void* gptr, void* lptr) {
  __builtin_amdgcn_global_load_lds(
      (const __attribute__((address_space(1))) void*)gptr,
      (__attribute__((address_space(3))) void*)lptr,
      16, 0, 0);
}

// ---------------------------------------------------------------------------
// Fused prep: blocks [0,2048) = gate softmax + x->bf16; blocks [2048,4096) =
// W[e][i][o] fp32 -> Wt[e][o][i] bf16 transpose.
// ---------------------------------------------------------------------------
__global__ __launch_bounds__(256) void prep_kernel(
    const float* __restrict__ x, const float* __restrict__ gw,
    const float* __restrict__ gb, float* __restrict__ g,
    bf16* __restrict__ xb, const float* __restrict__ w,
    bf16* __restrict__ wt) {
  __shared__ float tile[64][65];

  if (blockIdx.x < 2048) {
    const int lane = threadIdx.x & 63;
    const int wave = threadIdx.x >> 6;
    const int t = blockIdx.x * 4 + wave;
    const float* xr = x + (size_t)t * DIN;
    bf16* xbr = xb + (size_t)t * DIN;

    float acc[NE];
#pragma unroll
    for (int e = 0; e < NE; ++e) acc[e] = 0.f;

#pragma unroll
    for (int it = 0; it < 8; ++it) {
      const int i = it * 128 + lane * 2;
      const floatx2 xv = *(const floatx2*)(xr + i);
      union { bf16 b[2]; uint32_t u; } cv;
      cv.b[0] = (bf16)xv[0]; cv.b[1] = (bf16)xv[1];
      *(uint32_t*)(xbr + i) = cv.u;
      const floatx4 w00 = *(const floatx4*)(gw + (size_t)i * NE);
      const floatx4 w01 = *(const floatx4*)(gw + (size_t)i * NE + 4);
      const floatx4 w10 = *(const floatx4*)(gw + (size_t)(i + 1) * NE);
      const floatx4 w11 = *(const floatx4*)(gw + (size_t)(i + 1) * NE + 4);
#pragma unroll
      for (int e = 0; e < 4; ++e) {
        acc[e]     += xv[0] * w00[e] + xv[1] * w10[e];
        acc[e + 4] += xv[0] * w01[e] + xv[1] * w11[e];
      }
    }
#pragma unroll
    for (int e = 0; e < NE; ++e) {
#pragma unroll
      for (int off = 32; off > 0; off >>= 1)
        acc[e] += __shfl_xor(acc[e], off, 64);
    }
    float lg[NE];
    float mx = -3.0e38f;
#pragma unroll
    for (int e = 0; e < NE; ++e) { lg[e] = acc[e] + gb[e]; mx = fmaxf(mx, lg[e]); }
    float s = 0.f;
#pragma unroll
    for (int e = 0; e < NE; ++e) { lg[e] = __expf(lg[e] - mx); s += lg[e]; }
    const float inv = 1.f / s;
    if (lane == 0) {
      floatx4 o0, o1;
#pragma unroll
      for (int e = 0; e < 4; ++e) { o0[e] = lg[e] * inv; o1[e] = lg[e + 4] * inv; }
      *(floatx4*)(g + (size_t)t * NE) = o0;
      *(floatx4*)(g + (size_t)t * NE + 4) = o1;
    }
  } else {
    const int b = blockIdx.x - 2048;
    const int e = b >> 8;
    const int i0 = ((b >> 4) & 15) * 64;
    const int o0 = (b & 15) * 64;
    const int tid = threadIdx.x;
    const int c4 = (tid & 15) * 4;
    const int r = tid >> 4;

    const float* src = w + ((size_t)e * DIN + i0) * DOUT + o0;
#pragma unroll
    for (int rr = r; rr < 64; rr += 16) {
      const floatx4 v = *(const floatx4*)(src + (size_t)rr * DOUT + c4);
      tile[rr][c4] = v[0]; tile[rr][c4 + 1] = v[1];
      tile[rr][c4 + 2] = v[2]; tile[rr][c4 + 3] = v[3];
    }
    __syncthreads();
    bf16* dst = wt + ((size_t)e * DOUT + o0) * DIN + i0;
#pragma unroll
    for (int rr = r; rr < 64; rr += 16) {
      union { bf16 b[4]; uint64_t u; } cv;
#pragma unroll
      for (int j = 0; j < 4; ++j) cv.b[j] = (bf16)tile[c4 + j][rr];
      *(uint64_t*)(dst + (size_t)rr * DIN + c4) = cv.u;
    }
  }
}

// ---------------------------------------------------------------------------
// Fused MoE GEMM, R9 = R4 structure (e-outer, dual-acc, BK=64, two barriers,
// proven swizzle) with the wave tile as 2x2 of v_mfma_f32_32x32x16_bf16
// instead of 4x4 of 16x16x32: same 16B/lane A+B per MFMA but 2x FLOP ->
// fragment ds_read_b128 count HALVES (32 -> 16 per wave-window). DS pipe was
// the measured dominant term (~2259 of 3020 cyc/step); new budget ~1265.
// Read geometry per 16-lane group identical to R4's measured-0-conflict
// pattern. Layouts (m74/m101): A[m=lane&31][k=(lane>>5)*8+j];
// C/D col=lane&31, row=(reg&3)+8*(reg>>2)+4*(lane>>5).
// ---------------------------------------------------------------------------
__global__ __launch_bounds__(256, 2) void moe_gemm(
    const bf16* __restrict__ xb, const bf16* __restrict__ wt,
    const float* __restrict__ g, float* __restrict__ out) {
  __shared__ __align__(16) bf16 As[128 * 64];  // 16KB
  __shared__ __align__(16) bf16 Bs[128 * 64];  // 16KB

  const int tid = threadIdx.x;
  const int bm = blockIdx.x >> 3;
  const int bn = blockIdx.x & 7;
  const int lane = tid & 63;
  const int wave = tid >> 6;
  const int wm = wave >> 1, wn = wave & 1;
  const int l31 = lane & 31;        // row within 32-tile
  const int ln5 = lane >> 5;        // k-half selector
  const int kx = lane & 7;          // swizzle phase (row&7 == lane&7)

  // staging (R4 geometry, measured conflict-free): pass j covers rows
  // 32j..32j+31; unit u=tid+256j -> row=u>>3, pos=u&7, col=(pos^(row&7))*8.
  const int srow = tid >> 3;                                  // 0..31
  const int scol = (((tid & 7) ^ (srow & 7)) << 3);           // swizzled col

  const bf16* agp = xb + ((size_t)(bm * 128 + srow)) * DIN + scol;
  bf16* const alp = As + tid * 8;
  bf16* const blp = Bs + tid * 8;

  const int tok0 = bm * 128 + wm * 64;

  // C/D row-within-32-tile for each acc reg r: (r&3) + 8*(r>>2) + 4*ln5
  int rr16[16];
#pragma unroll
  for (int r = 0; r < 16; ++r) rr16[r] = (r & 3) + 8 * (r >> 2) + 4 * ln5;

  const floatx16 fz16 = {0.f,0.f,0.f,0.f,0.f,0.f,0.f,0.f,
                         0.f,0.f,0.f,0.f,0.f,0.f,0.f,0.f};
  floatx16 accF[2][2];
#pragma unroll
  for (int im = 0; im < 2; ++im)
#pragma unroll
    for (int in = 0; in < 2; ++in) accF[im][in] = fz16;

  for (int e = 0; e < NE; ++e) {
    const bf16* bgp = wt + ((size_t)e << 20) +
                      ((size_t)(bn * 128 + srow)) * DIN + scol;
    floatx16 accE[2][2];
#pragma unroll
    for (int im = 0; im < 2; ++im)
#pragma unroll
      for (int in = 0; in < 2; ++in) accE[im][in] = fz16;

    for (int k0 = 0; k0 < DIN; k0 += 64) {
      __syncthreads();
#pragma unroll
      for (int j = 0; j < 4; ++j) {
        async16(agp + k0 + (size_t)(32 * j) * DIN, alp + j * 2048);
        async16(bgp + k0 + (size_t)(32 * j) * DIN, blp + j * 2048);
      }
      __syncthreads();

#pragma unroll
      for (int ks = 0; ks < 4; ++ks) {
        const int kg = (((ks * 2 + ln5) ^ kx) << 3);  // swizzled 16B unit
        bf16x8 av[2], bv[2];
#pragma unroll
        for (int im = 0; im < 2; ++im)
          av[im] = *(const bf16x8*)(As + (wm * 64 + im * 32 + l31) * 64 + kg);
#pragma unroll
        for (int in = 0; in < 2; ++in)
          bv[in] = *(const bf16x8*)(Bs + (wn * 64 + in * 32 + l31) * 64 + kg);
#pragma unroll
        for (int im = 0; im < 2; ++im)
#pragma unroll
          for (int in = 0; in < 2; ++in)
            accE[im][in] = __builtin_amdgcn_mfma_f32_32x32x16_bf16(
                av[im], bv[in], accE[im][in], 0, 0, 0);
      }
    }

    // fold: accF += g[row, e] * accE
#pragma unroll
    for (int im = 0; im < 2; ++im) {
      float gv[16];
#pragma unroll
      for (int r = 0; r < 16; ++r)
        gv[r] = g[(size_t)(tok0 + im * 32 + rr16[r]) * NE + e];
#pragma unroll
      for (int in = 0; in < 2; ++in)
#pragma unroll
        for (int r = 0; r < 16; ++r)
          accF[im][in][r] += gv[r] * accE[im][in][r];
    }
  }

  // epilogue: col = lane&31 within 32-tile
#pragma unroll
  for (int im = 0; im < 2; ++im)
#pragma unroll
    for (int in = 0; in < 2; ++in) {
      const int col = bn * 128 + wn * 64 + in * 32 + l31;
#pragma unroll
      for (int r = 0; r < 16; ++r)
        out[(size_t)(tok0 + im * 32 + rr16[r]) * DOUT + col] =
            accF[im][in][r];
    }
}

// ---------------------------------------------------------------------------
extern "C" void kernel_launch(void* const* d_in, const int* in_sizes, int n_in,
                              void* d_out, int out_size, void* d_ws,
                              size_t ws_size, hipStream_t stream) {
  const float* x  = (const float*)d_in[0];
  const float* gw = (const float*)d_in[1];
  const float* gb = (const float*)d_in[2];
  const float* w  = (const float*)d_in[3];
  float* out = (float*)d_out;

  char* ws = (char*)d_ws;
  float* g  = (float*)ws;
  bf16* xb  = (bf16*)(ws + 262144);
  bf16* wt  = (bf16*)(ws + 262144 + (size_t)TOKENS * DIN * 2);

  prep_kernel<<<4096, 256, 0, stream>>>(x, gw, gb, g, xb, w, wt);
  moe_gemm<<<512, 256, 0, stream>>>(xb, wt, g, out);
}